// Round 1
// 636.569 us; speedup vs baseline: 1.9614x; 1.9614x over previous
//
#include <hip/hip_runtime.h>

#define BATCH 128
#define DIM 128
#define KP1 4097
#define NOUT 200000
#define MEM_N (NOUT * DIM)   // 25,600,000 floats per bank

// ---------------------------------------------------------------------------
// Momentum update of the 128 selected rows (after banks are copied to d_out).
// pos = mem[y]*0.5 + feat*0.5 ; out[y] = pos / ||pos||.
// Reads ORIGINAL memory (matches reference: gather+update both use pristine
// banks). Last-wins on duplicate y to match scatter .set semantics.
// ---------------------------------------------------------------------------
__global__ void momentum_rows(const float* __restrict__ l,
                              const float* __restrict__ ab,
                              const float* __restrict__ ori,
                              const int*   __restrict__ y,
                              const float* __restrict__ ml,
                              const float* __restrict__ mab,
                              const float* __restrict__ mo,
                              float* __restrict__ out_l,
                              float* __restrict__ out_ab,
                              float* __restrict__ out_o) {
    const int b  = blockIdx.x;
    const int yb = y[b];
    // last-wins: if a later batch element targets the same row, this block is dead
    for (int b2 = b + 1; b2 < BATCH; ++b2)
        if (y[b2] == yb) return;

    const int t = threadIdx.x;                 // 128 threads = 2 waves
    const size_t mbase = (size_t)yb * DIM + t;
    const int    fbase = b * DIM + t;

    float p0 = ml [mbase] * 0.5f + l  [fbase] * 0.5f;
    float p1 = mab[mbase] * 0.5f + ab [fbase] * 0.5f;
    float p2 = mo [mbase] * 0.5f + ori[fbase] * 0.5f;

    float s0 = p0 * p0, s1 = p1 * p1, s2 = p2 * p2;
#pragma unroll
    for (int off = 32; off > 0; off >>= 1) {
        s0 += __shfl_down(s0, off, 64);
        s1 += __shfl_down(s1, off, 64);
        s2 += __shfl_down(s2, off, 64);
    }
    __shared__ float red[3][2];
    if ((t & 63) == 0) { red[0][t >> 6] = s0; red[1][t >> 6] = s1; red[2][t >> 6] = s2; }
    __syncthreads();
    const float i0 = 1.0f / sqrtf(red[0][0] + red[0][1]);
    const float i1 = 1.0f / sqrtf(red[1][0] + red[1][1]);
    const float i2 = 1.0f / sqrtf(red[2][0] + red[2][1]);

    out_l [mbase] = p0 * i0;
    out_ab[mbase] = p1 * i1;
    out_o [mbase] = p2 * i2;
}

// ---------------------------------------------------------------------------
// Bank pass-through as a shader copy (SDMA memcpy only ran at ~1.3 TB/s;
// a grid-stride float4 copy runs at ~6 TB/s). 3 read + 3 write streams.
// ---------------------------------------------------------------------------
__global__ __launch_bounds__(256) void bank_copy(const float4* __restrict__ ml,
                                                 const float4* __restrict__ mab,
                                                 const float4* __restrict__ mo,
                                                 float4* __restrict__ ol,
                                                 float4* __restrict__ oab,
                                                 float4* __restrict__ oo) {
    const int n = MEM_N / 4;                       // 6,400,000 float4 per bank
    const int stride = gridDim.x * blockDim.x;
    for (int i = blockIdx.x * blockDim.x + threadIdx.x; i < n; i += stride) {
        ol [i] = ml [i];
        oab[i] = mab[i];
        oo [i] = mo [i];
    }
}

// ---------------------------------------------------------------------------
// Scores: 16-lane group = one (b,k) pair. The group reads each 512B bank row
// as 16 contiguous float4s (+ the second 256B half), so every wave-level load
// instruction covers 4 rows x 256B CONTIGUOUS -> full 64B-granule utilization
// (the old thread-per-pair layout issued 64 scattered 16B requests per
// instruction -> 2.8x HBM over-fetch, FETCH 2.27GB vs 805MB demand).
// Lane covers dims [lane*4, lane*4+4) u [64+lane*4, ...+4); 6 dots = 8 FMAs
// each + 4-level shfl_xor reduce over the group (VALU was 98% idle).
//   outs[0] = w_l  . ab    outs[1] = w_ab . l     outs[2] = w_l  . ori
//   outs[3] = w_ori. l     outs[4] = w_ori. ab    outs[5] = w_ab . ori
// ---------------------------------------------------------------------------
__global__ __launch_bounds__(256) void scores_kernel(const float* __restrict__ l,
                                                     const float* __restrict__ ab,
                                                     const float* __restrict__ ori,
                                                     const int*   __restrict__ idx,
                                                     const float* __restrict__ ml,
                                                     const float* __restrict__ mab,
                                                     const float* __restrict__ mo,
                                                     float* __restrict__ out) {
    const int b    = blockIdx.y;
    const int t    = threadIdx.x;
    const int g    = t >> 4;          // group 0..15 within block
    const int lane = t & 15;          // lane within group
    const int k    = blockIdx.x * 16 + g;
    if (k >= KP1) return;             // whole 16-lane group exits together

    const int row = idx[b * KP1 + k]; // same addr across group -> broadcast

    const float4* rl4 = (const float4*)(ml  + (size_t)row * DIM);
    const float4* ra4 = (const float4*)(mab + (size_t)row * DIM);
    const float4* ro4 = (const float4*)(mo  + (size_t)row * DIM);

    // 6 independent row loads in flight together
    float4 wl0 = rl4[lane], wl1 = rl4[lane + 16];
    float4 wa0 = ra4[lane], wa1 = ra4[lane + 16];
    float4 wo0 = ro4[lane], wo1 = ro4[lane + 16];

    const float4* fl4 = (const float4*)(l   + b * DIM);
    const float4* fa4 = (const float4*)(ab  + b * DIM);
    const float4* fo4 = (const float4*)(ori + b * DIM);
    float4 fl0 = fl4[lane], fl1 = fl4[lane + 16];
    float4 fa0 = fa4[lane], fa1 = fa4[lane + 16];
    float4 fo0 = fo4[lane], fo1 = fo4[lane + 16];

#define DOT8(w0, w1, f0, f1)                                                  \
    ((w0).x * (f0).x + (w0).y * (f0).y + (w0).z * (f0).z + (w0).w * (f0).w +  \
     (w1).x * (f1).x + (w1).y * (f1).y + (w1).z * (f1).z + (w1).w * (f1).w)

    float a0 = DOT8(wl0, wl1, fa0, fa1);
    float a1 = DOT8(wa0, wa1, fl0, fl1);
    float a2 = DOT8(wl0, wl1, fo0, fo1);
    float a3 = DOT8(wo0, wo1, fl0, fl1);
    float a4 = DOT8(wo0, wo1, fa0, fa1);
    float a5 = DOT8(wa0, wa1, fo0, fo1);
#undef DOT8

#pragma unroll
    for (int m = 8; m >= 1; m >>= 1) {
        a0 += __shfl_xor(a0, m, 16);
        a1 += __shfl_xor(a1, m, 16);
        a2 += __shfl_xor(a2, m, 16);
        a3 += __shfl_xor(a3, m, 16);
        a4 += __shfl_xor(a4, m, 16);
        a5 += __shfl_xor(a5, m, 16);
    }

    if (lane == 0) {
        const size_t plane = (size_t)BATCH * KP1;
        const size_t base  = (size_t)b * KP1 + k;
        out[base]             = a0;
        out[plane + base]     = a1;
        out[2 * plane + base] = a2;
        out[3 * plane + base] = a3;
        out[4 * plane + base] = a4;
        out[5 * plane + base] = a5;
    }
}

extern "C" void kernel_launch(void* const* d_in, const int* in_sizes, int n_in,
                              void* d_out, int out_size, void* d_ws, size_t ws_size,
                              hipStream_t stream) {
    const float* l   = (const float*)d_in[0];
    const float* ab  = (const float*)d_in[1];
    const float* ori = (const float*)d_in[2];
    const int*   y   = (const int*)d_in[3];
    const int*   idx = (const int*)d_in[4];
    const float* ml  = (const float*)d_in[5];
    const float* mab = (const float*)d_in[6];
    const float* mo  = (const float*)d_in[7];

    float* out        = (float*)d_out;
    float* out_scores = out;
    float* out_l  = out + (size_t)6 * BATCH * KP1;   // 3,146,496
    float* out_ab = out_l  + (size_t)MEM_N;
    float* out_o  = out_ab + (size_t)MEM_N;

    // 1) scores (reads only pristine inputs)
    dim3 sgrid((KP1 + 15) / 16, BATCH);
    scores_kernel<<<sgrid, 256, 0, stream>>>(l, ab, ori, idx, ml, mab, mo, out_scores);

    // 2) bank pass-through via shader copy (grid-stride, ~2048 blocks)
    bank_copy<<<2048, 256, 0, stream>>>((const float4*)ml, (const float4*)mab,
                                        (const float4*)mo,
                                        (float4*)out_l, (float4*)out_ab, (float4*)out_o);

    // 3) overwrite the 128 updated rows (after the copy)
    momentum_rows<<<BATCH, DIM, 0, stream>>>(l, ab, ori, y, ml, mab, mo,
                                             out_l, out_ab, out_o);
}

// Round 3
// 624.041 us; speedup vs baseline: 2.0007x; 1.0201x over previous
//
#include <hip/hip_runtime.h>

#define BATCH 128
#define DIM 128
#define KP1 4097
#define NOUT 200000
#define MEM_N (NOUT * DIM)   // 25,600,000 floats per bank

#define NCOPY 2048                    // copy-role blocks (grid-strided)
#define KBLKS ((KP1 + 15) / 16)       // 257 score block-columns
#define NSCORE (KBLKS * BATCH)        // 32,896 score blocks
#define NTOT (NCOPY + NSCORE)         // 34,944
#define RILV 17                       // interleave: every 17th block copies

// native clang vector: accepted by __builtin_nontemporal_{load,store}
typedef float fx4 __attribute__((ext_vector_type(4)));

// ---------------------------------------------------------------------------
// Momentum update of the 128 selected rows (after banks are copied to d_out).
// pos = mem[y]*0.5 + feat*0.5 ; out[y] = pos / ||pos||.
// Reads ORIGINAL memory. Last-wins on duplicate y (scatter .set semantics).
// Runs AFTER the fused kernel: kernel boundary orders these row writes after
// the copy blocks' writes to the same rows.
// ---------------------------------------------------------------------------
__global__ void momentum_rows(const float* __restrict__ l,
                              const float* __restrict__ ab,
                              const float* __restrict__ ori,
                              const int*   __restrict__ y,
                              const float* __restrict__ ml,
                              const float* __restrict__ mab,
                              const float* __restrict__ mo,
                              float* __restrict__ out_l,
                              float* __restrict__ out_ab,
                              float* __restrict__ out_o) {
    const int b  = blockIdx.x;
    const int yb = y[b];
    for (int b2 = b + 1; b2 < BATCH; ++b2)
        if (y[b2] == yb) return;      // a later batch element wins

    const int t = threadIdx.x;        // 128 threads = 2 waves
    const size_t mbase = (size_t)yb * DIM + t;
    const int    fbase = b * DIM + t;

    float p0 = ml [mbase] * 0.5f + l  [fbase] * 0.5f;
    float p1 = mab[mbase] * 0.5f + ab [fbase] * 0.5f;
    float p2 = mo [mbase] * 0.5f + ori[fbase] * 0.5f;

    float s0 = p0 * p0, s1 = p1 * p1, s2 = p2 * p2;
#pragma unroll
    for (int off = 32; off > 0; off >>= 1) {
        s0 += __shfl_down(s0, off, 64);
        s1 += __shfl_down(s1, off, 64);
        s2 += __shfl_down(s2, off, 64);
    }
    __shared__ float red[3][2];
    if ((t & 63) == 0) { red[0][t >> 6] = s0; red[1][t >> 6] = s1; red[2][t >> 6] = s2; }
    __syncthreads();
    const float i0 = 1.0f / sqrtf(red[0][0] + red[0][1]);
    const float i1 = 1.0f / sqrtf(red[1][0] + red[1][1]);
    const float i2 = 1.0f / sqrtf(red[2][0] + red[2][1]);

    out_l [mbase] = p0 * i0;
    out_ab[mbase] = p1 * i1;
    out_o [mbase] = p2 * i2;
}

// ---------------------------------------------------------------------------
// Fused kernel. Block role by interleave: blockIdx.x % 17 == 0 (and within
// the first 2048 such blocks) -> grid-strided bank copy; else -> one score
// block (16 groups x 16 lanes, group = one (b,k) pair).
// Rationale: scores alone is gather/latency-limited (~3 TB/s); the copy is
// pure streaming. Interleaving the roles in one dispatch keeps the HBM
// pipeline full the whole time instead of running the two phases serially.
// Copy uses nontemporal ld/st so its 614 MB stream doesn't evict the bank
// rows scores re-hits in L2/L3 (~2.6x read reuse).
// ---------------------------------------------------------------------------
__global__ __launch_bounds__(256) void fused_kernel(const float* __restrict__ l,
                                                    const float* __restrict__ ab,
                                                    const float* __restrict__ ori,
                                                    const int*   __restrict__ idx,
                                                    const float* __restrict__ ml,
                                                    const float* __restrict__ mab,
                                                    const float* __restrict__ mo,
                                                    float* __restrict__ out,
                                                    float* __restrict__ out_l,
                                                    float* __restrict__ out_ab,
                                                    float* __restrict__ out_o) {
    const int bid = blockIdx.x;
    const int c   = bid / RILV;
    const int r   = bid - c * RILV;

    if (r == 0 && c < NCOPY) {
        // ---- copy role: grid-stride over 6.4M fx4 per bank ----
        const fx4* ml4  = (const fx4*)ml;
        const fx4* mab4 = (const fx4*)mab;
        const fx4* mo4  = (const fx4*)mo;
        fx4* ol4  = (fx4*)out_l;
        fx4* oab4 = (fx4*)out_ab;
        fx4* oo4  = (fx4*)out_o;
        const int n = MEM_N / 4;
        const int stride = NCOPY * 256;
        for (int i = c * 256 + threadIdx.x; i < n; i += stride) {
            fx4 a = __builtin_nontemporal_load(ml4 + i);
            fx4 d = __builtin_nontemporal_load(mab4 + i);
            fx4 e = __builtin_nontemporal_load(mo4 + i);
            __builtin_nontemporal_store(a, ol4 + i);
            __builtin_nontemporal_store(d, oab4 + i);
            __builtin_nontemporal_store(e, oo4 + i);
        }
        return;
    }

    // ---- score role ----
    // scores-block index: subtract # of copy blocks with id < bid
    const int ncb = (r == 0) ? NCOPY : ((c + 1 < NCOPY) ? c + 1 : NCOPY);
    const int sb  = bid - ncb;            // 0 .. NSCORE-1
    const int b   = sb / KBLKS;
    const int kb  = sb - b * KBLKS;

    const int t    = threadIdx.x;
    const int g    = t >> 4;              // group 0..15
    const int lane = t & 15;
    const int k    = kb * 16 + g;
    if (k >= KP1) return;                 // whole group exits together

    const int row = idx[b * KP1 + k];     // broadcast within group

    const float4* rl4 = (const float4*)(ml  + (size_t)row * DIM);
    const float4* ra4 = (const float4*)(mab + (size_t)row * DIM);
    const float4* ro4 = (const float4*)(mo  + (size_t)row * DIM);

    // 6 independent 16B row loads in flight per lane (contiguous per group)
    float4 wl0 = rl4[lane], wl1 = rl4[lane + 16];
    float4 wa0 = ra4[lane], wa1 = ra4[lane + 16];
    float4 wo0 = ro4[lane], wo1 = ro4[lane + 16];

    const float4* fl4 = (const float4*)(l   + b * DIM);
    const float4* fa4 = (const float4*)(ab  + b * DIM);
    const float4* fo4 = (const float4*)(ori + b * DIM);
    float4 fl0 = fl4[lane], fl1 = fl4[lane + 16];
    float4 fa0 = fa4[lane], fa1 = fa4[lane + 16];
    float4 fo0 = fo4[lane], fo1 = fo4[lane + 16];

#define DOT8(w0, w1, f0, f1)                                                  \
    ((w0).x * (f0).x + (w0).y * (f0).y + (w0).z * (f0).z + (w0).w * (f0).w +  \
     (w1).x * (f1).x + (w1).y * (f1).y + (w1).z * (f1).z + (w1).w * (f1).w)

    float a0 = DOT8(wl0, wl1, fa0, fa1);
    float a1 = DOT8(wa0, wa1, fl0, fl1);
    float a2 = DOT8(wl0, wl1, fo0, fo1);
    float a3 = DOT8(wo0, wo1, fl0, fl1);
    float a4 = DOT8(wo0, wo1, fa0, fa1);
    float a5 = DOT8(wa0, wa1, fo0, fo1);
#undef DOT8

#pragma unroll
    for (int m = 8; m >= 1; m >>= 1) {
        a0 += __shfl_xor(a0, m, 16);
        a1 += __shfl_xor(a1, m, 16);
        a2 += __shfl_xor(a2, m, 16);
        a3 += __shfl_xor(a3, m, 16);
        a4 += __shfl_xor(a4, m, 16);
        a5 += __shfl_xor(a5, m, 16);
    }

    if (lane == 0) {
        const size_t plane = (size_t)BATCH * KP1;
        const size_t base  = (size_t)b * KP1 + k;
        out[base]             = a0;
        out[plane + base]     = a1;
        out[2 * plane + base] = a2;
        out[3 * plane + base] = a3;
        out[4 * plane + base] = a4;
        out[5 * plane + base] = a5;
    }
}

extern "C" void kernel_launch(void* const* d_in, const int* in_sizes, int n_in,
                              void* d_out, int out_size, void* d_ws, size_t ws_size,
                              hipStream_t stream) {
    const float* l   = (const float*)d_in[0];
    const float* ab  = (const float*)d_in[1];
    const float* ori = (const float*)d_in[2];
    const int*   y   = (const int*)d_in[3];
    const int*   idx = (const int*)d_in[4];
    const float* ml  = (const float*)d_in[5];
    const float* mab = (const float*)d_in[6];
    const float* mo  = (const float*)d_in[7];

    float* out        = (float*)d_out;
    float* out_scores = out;
    float* out_l  = out + (size_t)6 * BATCH * KP1;   // 3,146,496
    float* out_ab = out_l  + (size_t)MEM_N;
    float* out_o  = out_ab + (size_t)MEM_N;

    // 1) fused scores + bank pass-through (reads only pristine inputs)
    fused_kernel<<<NTOT, 256, 0, stream>>>(l, ab, ori, idx, ml, mab, mo,
                                           out_scores, out_l, out_ab, out_o);

    // 2) overwrite the 128 updated rows (ordered after the copy by the
    //    kernel boundary)
    momentum_rows<<<BATCH, DIM, 0, stream>>>(l, ab, ori, y, ml, mab, mo,
                                             out_l, out_ab, out_o);
}